// Round 9
// baseline (266.277 us; speedup 1.0000x reference)
//
#include <hip/hip_runtime.h>

// Atom_Atom_embedding_MP: batched KNN (k=16, self-excluded) + 3 MP layers.
//
// R7 (resubmitted R8 after infra failure):
// (a) knn selection: replaced 16-round extract-min (800 VALU + 192 swizzle
// /query) with exact 31-step radix bisection on the d2 BIT domain (u32 order-
// isomorphic) + unordered ballot-compact write (order irrelevant: consumer
// sums over k). Running shrink uses the same exact bisect -> tau tight ->
// ~1 shrink/query. (b) layers: lane = (point, out-channel); W1 cols c,c+16 +
// W2 col c live in VGPRs (one-time coalesced load), k is a serial loop with
// broadcast gathers; k-sum is free (register accumulate); o=32 on masked
// lane15 with W1[:,32] in SGPRs. Kills s_load streaming stalls + shfl k-sum.

#define N_PTS 16384
#define D 16
#define DIN 33
#define NEG 0.2f
#define GEPS 1e-5f
#define INFF 3.0e38f
#define INFU 0x7f800000u
#define SHRINK_AT 192

__global__ __launch_bounds__(256) void prep_kernel(const float* __restrict__ x,
                                                   float4* __restrict__ xyz4, int n) {
  int i = blockIdx.x * 256 + threadIdx.x;
  if (i < n) xyz4[i] = make_float4(x[3*i], x[3*i+1], x[3*i+2], 0.f);
}

// Exact 16th-smallest bit pattern of pool (u-rows) via 31-step radix bisection.
// Invariant: cnt(lo) < 16 <= cnt(hi); returns lo = 16th smallest value.
__device__ __forceinline__ unsigned bisect16(unsigned u0, unsigned u1,
                                             unsigned u2, unsigned u3) {
  unsigned lo = 0u, hi = 0x7f800001u;
  for (int it = 0; it < 31; ++it) {
    const unsigned mid = lo + ((hi - lo) >> 1);
    const int c = __popcll(__ballot(u0 < mid)) + __popcll(__ballot(u1 < mid))
                + __popcll(__ballot(u2 < mid)) + __popcll(__ballot(u3 < mid));
    if (c >= 16) hi = mid; else lo = mid;
  }
  return lo;
}

// Tighten tau to EXACT 16th-smallest-so-far; compact pool to entries <= tau
// (keeps all current top-16 members incl. ties). Returns new count (>=16).
__device__ __forceinline__ int pool_shrink(float* __restrict__ pd, int* __restrict__ pi,
                                           int pcount, float& tau, int l,
                                           unsigned long long lmask) {
  __asm__ volatile("s_waitcnt lgkmcnt(0)" ::: "memory");
  unsigned u0 = INFU, u1 = INFU, u2 = INFU, u3 = INFU;
  int j0 = 0, j1 = 0, j2 = 0, j3 = 0;
  if (l       < pcount) { u0 = __float_as_uint(pd[l]);       j0 = pi[l]; }
  if (l + 64  < pcount) { u1 = __float_as_uint(pd[l + 64]);  j1 = pi[l + 64]; }
  if (l + 128 < pcount) { u2 = __float_as_uint(pd[l + 128]); j2 = pi[l + 128]; }
  if (l + 192 < pcount) { u3 = __float_as_uint(pd[l + 192]); j3 = pi[l + 192]; }
  const unsigned t = bisect16(u0, u1, u2, u3);
  tau = __uint_as_float(t);              // scan keeps strict d2 < tau
  int base = 0;
  { const bool k = u0 <= t; const unsigned long long m = __ballot(k);
    if (k) { const int pos = base + __popcll(m & lmask);
             pd[pos] = __uint_as_float(u0); pi[pos] = j0; }
    base += __popcll(m); }
  { const bool k = u1 <= t; const unsigned long long m = __ballot(k);
    if (k) { const int pos = base + __popcll(m & lmask);
             pd[pos] = __uint_as_float(u1); pi[pos] = j1; }
    base += __popcll(m); }
  { const bool k = u2 <= t; const unsigned long long m = __ballot(k);
    if (k) { const int pos = base + __popcll(m & lmask);
             pd[pos] = __uint_as_float(u2); pi[pos] = j2; }
    base += __popcll(m); }
  { const bool k = u3 <= t; const unsigned long long m = __ballot(k);
    if (k) { const int pos = base + __popcll(m & lmask);
             pd[pos] = __uint_as_float(u3); pi[pos] = j3; }
    base += __popcll(m); }
  return base;
}

// Final: exact top-16 SET (unordered) written straight to output.
__device__ __forceinline__ void pool_final16(const float* __restrict__ pd,
                                             const int* __restrict__ pi,
                                             int pcount, int q, int l,
                                             int* __restrict__ knn_idx,
                                             float* __restrict__ knn_d2) {
  __asm__ volatile("s_waitcnt lgkmcnt(0)" ::: "memory");
  const unsigned long long lmask = (1ull << l) - 1ull;
  unsigned u0 = INFU, u1 = INFU, u2 = INFU, u3 = INFU;
  int j0 = 0, j1 = 0, j2 = 0, j3 = 0;
  if (l       < pcount) { u0 = __float_as_uint(pd[l]);       j0 = pi[l]; }
  if (l + 64  < pcount) { u1 = __float_as_uint(pd[l + 64]);  j1 = pi[l + 64]; }
  if (l + 128 < pcount) { u2 = __float_as_uint(pd[l + 128]); j2 = pi[l + 128]; }
  if (l + 192 < pcount) { u3 = __float_as_uint(pd[l + 192]); j3 = pi[l + 192]; }
  const unsigned t = bisect16(u0, u1, u2, u3);
  int base = 0;
  // strict-less entries (count < 16 by definition of t)
  { const bool k = u0 < t; const unsigned long long m = __ballot(k);
    if (k) { const int pos = base + __popcll(m & lmask);
             knn_idx[q*16+pos] = j0; knn_d2[q*16+pos] = __uint_as_float(u0); }
    base += __popcll(m); }
  { const bool k = u1 < t; const unsigned long long m = __ballot(k);
    if (k) { const int pos = base + __popcll(m & lmask);
             knn_idx[q*16+pos] = j1; knn_d2[q*16+pos] = __uint_as_float(u1); }
    base += __popcll(m); }
  { const bool k = u2 < t; const unsigned long long m = __ballot(k);
    if (k) { const int pos = base + __popcll(m & lmask);
             knn_idx[q*16+pos] = j2; knn_d2[q*16+pos] = __uint_as_float(u2); }
    base += __popcll(m); }
  { const bool k = u3 < t; const unsigned long long m = __ballot(k);
    if (k) { const int pos = base + __popcll(m & lmask);
             knn_idx[q*16+pos] = j3; knn_d2[q*16+pos] = __uint_as_float(u3); }
    base += __popcll(m); }
  // equals fill the remaining slots, capped at 16
  const float tf = __uint_as_float(t);
  { const bool k = u0 == t; const unsigned long long m = __ballot(k);
    if (k) { const int pos = base + __popcll(m & lmask);
             if (pos < 16) { knn_idx[q*16+pos] = j0; knn_d2[q*16+pos] = tf; } }
    base += __popcll(m); }
  { const bool k = u1 == t; const unsigned long long m = __ballot(k);
    if (k) { const int pos = base + __popcll(m & lmask);
             if (pos < 16) { knn_idx[q*16+pos] = j1; knn_d2[q*16+pos] = tf; } }
    base += __popcll(m); }
  { const bool k = u2 == t; const unsigned long long m = __ballot(k);
    if (k) { const int pos = base + __popcll(m & lmask);
             if (pos < 16) { knn_idx[q*16+pos] = j2; knn_d2[q*16+pos] = tf; } }
    base += __popcll(m); }
  { const bool k = u3 == t; const unsigned long long m = __ballot(k);
    if (k) { const int pos = base + __popcll(m & lmask);
             if (pos < 16) { knn_idx[q*16+pos] = j3; knn_d2[q*16+pos] = tf; } }
    base += __popcll(m); }
}

__global__ __launch_bounds__(256) void knn_kernel(const float4* __restrict__ xyz4,
                                                  const int* __restrict__ batch,
                                                  int* __restrict__ knn_idx,
                                                  float* __restrict__ knn_d2, int n) {
  __shared__ float pd[4][256];
  __shared__ int   pi[4][256];
  const int tid = threadIdx.x;
  const int w = tid >> 6;
  const int l = tid & 63;
  const int q = blockIdx.x * 4 + w;

  const float4 Q = xyz4[q];
  const int b = batch[q];
  int lo, hi;
  { int a = 0, c = n; while (a < c) { int m = (a + c) >> 1; if (batch[m] <  b) a = m + 1; else c = m; } lo = a; }
  { int a = lo, c = n; while (a < c) { int m = (a + c) >> 1; if (batch[m] <= b) a = m + 1; else c = m; } hi = a; }

  const unsigned long long lmask = (1ull << l) - 1ull;
  float tau = INFF;
  int pcount = 0;                     // wave-uniform (ballot-derived)

  for (int j0 = lo; j0 < hi; j0 += 64) {
    const int j = j0 + l;
    bool pass = false; float d2 = 0.f;
    if (j < hi) {
      const float4 P = xyz4[j];
      const float dx = Q.x - P.x, dy = Q.y - P.y, dz = Q.z - P.z;
      d2 = dx*dx + dy*dy + dz*dz;
      pass = (d2 < tau) && (j != q);
    }
    const unsigned long long m = __ballot(pass);
    if (m) {
      if (pass) {
        const int pos = pcount + __popcll(m & lmask);
        pd[w][pos] = d2; pi[w][pos] = j;
      }
      pcount += __popcll(m);
      if (pcount >= SHRINK_AT) {      // cap 256: pre-append <=191, +64 max
        pcount = pool_shrink(&pd[w][0], &pi[w][0], pcount, tau, l, lmask);
      }
    }
  }
  pool_final16(&pd[w][0], &pi[w][0], pcount, q, l, knn_idx, knn_d2);
}

__device__ __forceinline__ void load16(const float4* __restrict__ base, int row, float* dst) {
  float4 a = base[row*4+0], b = base[row*4+1], c = base[row*4+2], d = base[row*4+3];
  dst[0]=a.x;  dst[1]=a.y;  dst[2]=a.z;  dst[3]=a.w;
  dst[4]=b.x;  dst[5]=b.y;  dst[6]=b.z;  dst[7]=b.w;
  dst[8]=c.x;  dst[9]=c.y;  dst[10]=c.z; dst[11]=c.w;
  dst[12]=d.x; dst[13]=d.y; dst[14]=d.z; dst[15]=d.w;
}

__device__ __forceinline__ float lrelu(float x) {
  return fmaxf(x, 0.f) + NEG * fminf(x, 0.f);
}

// Layer v2: lane = (point, out-channel c). W1 cols {c, c+16} and W2 col c in
// VGPRs (coalesced one-time load); serial k-loop with broadcast neighbor
// gathers; lrelu-sum over k accumulates in registers (no shfl k-sum).
// Output o=32: W1[:,32]/b1[32] are wave-uniform (s_load) -> masked lane 15.
__global__ __launch_bounds__(256) void layer_kernel(
    const float* __restrict__ in, const int* __restrict__ knn_idx,
    const float* __restrict__ knn_d2,
    const float* __restrict__ W1, const float* __restrict__ b1,
    const float* __restrict__ W2, const float* __restrict__ b2,
    const float* __restrict__ gamma, const float* __restrict__ beta,
    float* __restrict__ outb) {
  const int tid = threadIdx.x;
  const int g = tid >> 4;                 // point slot within block
  const int c = tid & 15;                 // out-channel lane
  const int p = blockIdx.x * 16 + g;

  __shared__ float sH[16][36];            // per-point h-sum exchange (33 used)

  float w1a[DIN], w1b[DIN], w2c[DIN];
#pragma unroll
  for (int i = 0; i < DIN; ++i) {
    w1a[i] = W1[i*DIN + c];               // coalesced: lanes cover 64B
    w1b[i] = W1[i*DIN + 16 + c];
    w2c[i] = W2[i*D + c];
  }
  const float b1a = b1[c], b1b = b1[16 + c];

  const float4* in4 = (const float4*)in;
  float s[16];
  load16(in4, p, s);                      // own features (broadcast in group)

  const int*   kidx = knn_idx + p * 16;
  const float* kd2  = knn_d2  + p * 16;

  float hsA = 0.f, hsB = 0.f, hsZ = 0.f;
#pragma unroll 2
  for (int k = 0; k < 16; ++k) {
    const int   nb = kidx[k];             // uniform per group
    const float dk = kd2[k];
    float nf[16];
    load16(in4, nb, nf);                  // broadcast gather
    float ha = b1a + dk * w1a[32];
    float hb = b1b + dk * w1b[32];
#pragma unroll
    for (int i = 0; i < 16; ++i) {
      ha += s[i]  * w1a[i];
      ha += nf[i] * w1a[16 + i];
      hb += s[i]  * w1b[i];
      hb += nf[i] * w1b[16 + i];
    }
    hsA += lrelu(ha);
    hsB += lrelu(hb);
    if (c == 15) {                        // o = 32 (W1[:,32] uniform -> SGPRs)
      float hz = b1[32] + dk * W1[32*DIN + 32];
#pragma unroll
      for (int i = 0; i < 16; ++i) {
        hz += s[i]  * W1[i*DIN + 32];
        hz += nf[i] * W1[(16 + i)*DIN + 32];
      }
      hsZ += lrelu(hz);
    }
  }

  // exchange h-sums within the 16-lane group (same wave: no barrier)
  sH[g][c]      = hsA;
  sH[g][16 + c] = hsB;
  if (c == 15) sH[g][32] = hsZ;

  float m = b2[c];
#pragma unroll
  for (int i = 0; i < DIN; ++i) m += sH[g][i] * w2c[i];

  // GroupNorm(groups=2): 8-channel groups -> 8-lane shfl reductions
  float sum = m;
  sum += __shfl_xor(sum, 1); sum += __shfl_xor(sum, 2); sum += __shfl_xor(sum, 4);
  const float mu = sum * 0.125f;
  const float dd = m - mu;
  float sq = dd * dd;
  sq += __shfl_xor(sq, 1); sq += __shfl_xor(sq, 2); sq += __shfl_xor(sq, 4);
  const float var = sq * 0.125f;
  float yv = dd * (1.0f / sqrtf(var + GEPS));
  yv = yv * gamma[c] + beta[c];

  outb[p * 16 + c] = in[p * 16 + c] + lrelu(yv);
}

extern "C" void kernel_launch(void* const* d_in, const int* in_sizes, int n_in,
                              void* d_out, int out_size, void* d_ws, size_t ws_size,
                              hipStream_t stream) {
  const float* x     = (const float*)d_in[0];
  const float* yat   = (const float*)d_in[2];
  const float* W1    = (const float*)d_in[3];
  const float* b1    = (const float*)d_in[4];
  const float* W2    = (const float*)d_in[5];
  const float* b2    = (const float*)d_in[6];
  const float* gamma = (const float*)d_in[7];
  const float* beta  = (const float*)d_in[8];
  const int*   xb    = (const int*)d_in[9];
  float* out = (float*)d_out;

  char* ws = (char*)d_ws;
  float4* xyz4 = (float4*)(ws);
  int*    kidx = (int*)  (ws + 262144);
  float*  kd2  = (float*)(ws + 262144 + 1048576);
  float*  bufA = (float*)(ws + 262144 + 2*1048576);
  float*  bufB = (float*)(ws + 262144 + 3*1048576);

  prep_kernel<<<N_PTS / 256, 256, 0, stream>>>(x, xyz4, N_PTS);
  knn_kernel<<<N_PTS / 4, 256, 0, stream>>>(xyz4, xb, kidx, kd2, N_PTS);
  layer_kernel<<<N_PTS / 16, 256, 0, stream>>>(yat,  kidx, kd2,
      W1 + 0*DIN*DIN, b1 + 0*DIN, W2 + 0*DIN*D, b2 + 0*D, gamma + 0*D, beta + 0*D, bufA);
  layer_kernel<<<N_PTS / 16, 256, 0, stream>>>(bufA, kidx, kd2,
      W1 + 1*DIN*DIN, b1 + 1*DIN, W2 + 1*DIN*D, b2 + 1*D, gamma + 1*D, beta + 1*D, bufB);
  layer_kernel<<<N_PTS / 16, 256, 0, stream>>>(bufB, kidx, kd2,
      W1 + 2*DIN*DIN, b1 + 2*DIN, W2 + 2*DIN*D, b2 + 2*D, gamma + 2*D, beta + 2*D, out);
}